// Round 4
// baseline (866.731 us; speedup 1.0000x reference)
//
#include <hip/hip_runtime.h>
#include <hip/hip_bf16.h>
#include <cstdint>

#define B_ 8
#define S_ 2048
#define E_ 1024

using u16 = unsigned short;

typedef __bf16 bf16x8 __attribute__((ext_vector_type(8)));
typedef float f32x4 __attribute__((ext_vector_type(4)));

__device__ inline u16 f2bf(float f) {
  uint32_t u = __float_as_uint(f);
  uint32_t r = (u + 0x7fffu + ((u >> 16) & 1u)) >> 16;
  return (u16)r;
}

// ---------------------------------------------------------------------------
// Generic NT GEMM: C[m,n] = sum_k A[m,k] * B[n,k]  (bf16, K contiguous).
// 128x128 tile, BK=32, 4 waves x (64x64 via 4x4 MFMA 16x16x32). m97 staging.
// XCD-aware swizzle: linear id d -> XCD d%8 (assumed); each XCD walks 4x8
// block super-tiles (A 4 panels + B 8 panels ~3MB @K=1024 -> fits 4MB L2).
// TRANS: store C transposed. MASKSCALE: scores epilogue (x1/32, col mask).
// QKVSPLIT: N=3072 fused QKV; n<2048 -> C (ld 2048), n>=2048 -> Vt transposed.
// ---------------------------------------------------------------------------
template<bool HAS_BIAS, bool RELU, bool HAS_RES, bool OUT_BF16, bool TRANS,
         bool MASKSCALE, bool QKVSPLIT>
__global__ __launch_bounds__(256) void gemm_nt(
    const u16* __restrict__ A, const u16* __restrict__ B, void* __restrict__ C,
    const float* __restrict__ bias, const float* __restrict__ res,
    int lda, int ldb, int ldc, int K,
    long long strideA, long long strideB, long long strideC,
    const void* __restrict__ mask, const int* __restrict__ flag, int b0,
    u16* __restrict__ vt)
{
  __shared__ u16 lA[128 * 32];
  __shared__ u16 lB[128 * 32];

  const int tid  = threadIdx.x;
  const int lane = tid & 63;
  const int wave = tid >> 6;

  // ---- block swizzle ----
  const int GM = 4, GN = 8;
  const int nbn = gridDim.x, nbm = gridDim.y, nz = gridDim.z;
  int bm, bn, bz;
  {
    const int total = nbn * nbm * nz;
    const long long lin = blockIdx.x +
        (long long)nbn * (blockIdx.y + (long long)nbm * blockIdx.z);
    if ((nbm % GM) == 0 && (nbn % GN) == 0 && (total % (8 * GM * GN)) == 0) {
      const int xcd = (int)(lin & 7);
      const int loc = (int)(lin >> 3);
      const int sper = GM * GN;                 // 32
      const int super = (loc / sper) * 8 + xcd; // supers striped across XCDs
      const int ins   = loc % sper;
      const int spz = (nbm / GM) * (nbn / GN);
      bz = super / spz;
      const int s2 = super % spz;
      const int sm = s2 % (nbm / GM);
      const int sn = s2 / (nbm / GM);
      bm = sm * GM + (ins % GM);
      bn = sn * GN + (ins / GM);
    } else { bm = blockIdx.y; bn = blockIdx.x; bz = blockIdx.z; }
  }

  const u16* Ab = A + (long long)bz * strideA;
  const u16* Bb = B + (long long)bz * strideB;

  const bool stageA = (wave < 2);
  const int  wpart  = (wave & 1) * 64;
  const int  srow   = lane >> 2;
  const int  scol   = (lane & 3) * 8;
  const int  ld     = stageA ? lda : ldb;
  const u16* gsrc   = stageA
      ? (Ab + (long long)(bm * 128 + wpart + srow) * lda + scol)
      : (Bb + (long long)(bn * 128 + wpart + srow) * ldb + scol);
  u16* ldst = (stageA ? lA : lB) + wpart * 32;

  f32x4 acc[4][4];
#pragma unroll
  for (int i = 0; i < 4; ++i)
#pragma unroll
    for (int j = 0; j < 4; ++j)
      acc[i][j] = (f32x4){0.f, 0.f, 0.f, 0.f};

  const int wm = (wave >> 1) * 64;
  const int wn = (wave & 1) * 64;
  const u16* pA = lA + (wm + (lane & 15)) * 32 + (lane >> 4) * 8;
  const u16* pB = lB + (wn + (lane & 15)) * 32 + (lane >> 4) * 8;

  const int nk = K >> 5;
  for (int kt = 0; kt < nk; ++kt) {
    __syncthreads();
    const u16* g = gsrc + kt * 32;
#pragma unroll
    for (int c = 0; c < 4; ++c) {
      __builtin_amdgcn_global_load_lds(
          (const __attribute__((address_space(1))) void*)(g + (long long)c * 16 * ld),
          (__attribute__((address_space(3))) void*)(ldst + c * 16 * 32),
          16, 0, 0);
    }
    __syncthreads();

    bf16x8 af[4], bfr[4];
#pragma unroll
    for (int i = 0; i < 4; ++i) af[i] = *(const bf16x8*)(pA + i * 16 * 32);
#pragma unroll
    for (int j = 0; j < 4; ++j) bfr[j] = *(const bf16x8*)(pB + j * 16 * 32);
#pragma unroll
    for (int i = 0; i < 4; ++i)
#pragma unroll
      for (int j = 0; j < 4; ++j)
        acc[i][j] = __builtin_amdgcn_mfma_f32_16x16x32_bf16(af[i], bfr[j], acc[i][j], 0, 0, 0);
  }

  // epilogue: C/D layout col = lane&15, row = (lane>>4)*4 + reg  [m89/m91]
  const int rb = wm + (lane >> 4) * 4;
  const int cb = wn + (lane & 15);
  const float* resb = (const float*)C;
  if (HAS_RES) resb = res + (long long)bz * strideC;
  u16*   cb16 = (u16*)C   + (long long)bz * strideC;
  float* cf32 = (float*)C + (long long)bz * strideC;

  bool u8m = false;
  const unsigned char* m8 = nullptr;
  const int* m32 = nullptr;
  if (MASKSCALE) {
    u8m = (*flag != 0);
    m8  = (const unsigned char*)mask + (long long)(b0 + bz) * S_;
    m32 = (const int*)mask + (long long)(b0 + bz) * S_;
  }

#pragma unroll
  for (int j = 0; j < 4; ++j) {
    const int gn = bn * 128 + cb + j * 16;
    const float bvv = HAS_BIAS ? bias[gn] : 0.f;
    bool masked = false;
    if (MASKSCALE) masked = u8m ? (m8[gn] != 0) : (m32[gn] != 0);
#pragma unroll
    for (int i = 0; i < 4; ++i) {
#pragma unroll
      for (int r = 0; r < 4; ++r) {
        const int gm = bm * 128 + rb + i * 16 + r;
        float v = acc[i][j][r] + bvv;
        if (MASKSCALE) { v *= 0.03125f; if (masked) v = -3.0e38f; }
        if (RELU) v = fmaxf(v, 0.f);
        if (QKVSPLIT) {
          if (gn < 2 * E_) {
            cb16[(long long)gm * (2 * E_) + gn] = f2bf(v);
          } else {
            const int e  = gn - 2 * E_;
            const int bl = gm >> 11;           // local batch
            const int rr = gm & (S_ - 1);
            vt[((long long)bl * E_ + e) * S_ + rr] = f2bf(v);
          }
        } else {
          const long long idx = TRANS ? ((long long)gn * ldc + gm)
                                      : ((long long)gm * ldc + gn);
          float vv = v;
          if (HAS_RES) vv += resb[idx];
          if (OUT_BF16) cb16[idx] = f2bf(vv);
          else          cf32[idx] = vv;
        }
      }
    }
  }
}

// ---------------------------------------------------------------------------
__global__ __launch_bounds__(256) void layernorm_kernel(
    const float* __restrict__ x, const float* __restrict__ w,
    const float* __restrict__ b, u16* __restrict__ out)
{
  const int row = blockIdx.x;
  const int tid = threadIdx.x;
  const float4 v = ((const float4*)(x + (long long)row * E_))[tid];
  float s  = v.x + v.y + v.z + v.w;
  float s2 = v.x * v.x + v.y * v.y + v.z * v.z + v.w * v.w;
#pragma unroll
  for (int o = 32; o >= 1; o >>= 1) { s += __shfl_xor(s, o); s2 += __shfl_xor(s2, o); }
  __shared__ float rs[4], rs2[4];
  const int wave = tid >> 6, lane = tid & 63;
  if (lane == 0) { rs[wave] = s; rs2[wave] = s2; }
  __syncthreads();
  s  = rs[0] + rs[1] + rs[2] + rs[3];
  s2 = rs2[0] + rs2[1] + rs2[2] + rs2[3];
  const float mu   = s * (1.f / E_);
  const float var  = s2 * (1.f / E_) - mu * mu;
  const float rstd = rsqrtf(var + 1e-5f);
  const float4 wv = ((const float4*)w)[tid];
  const float4 bv = ((const float4*)b)[tid];
  ushort4 o;
  o.x = f2bf((v.x - mu) * rstd * wv.x + bv.x);
  o.y = f2bf((v.y - mu) * rstd * wv.y + bv.y);
  o.z = f2bf((v.z - mu) * rstd * wv.z + bv.z);
  o.w = f2bf((v.w - mu) * rstd * wv.w + bv.w);
  ((ushort4*)(out + (long long)row * E_))[tid] = o;
}

// ---------------------------------------------------------------------------
// in-place softmax over one bf16 row of S_ (scale+mask already applied)
__global__ __launch_bounds__(256) void softmax_bf16_kernel(u16* __restrict__ sp)
{
  const int row = blockIdx.x;
  const int tid = threadIdx.x;
  u16* pr = sp + (long long)row * S_;
  uint4 raw = ((uint4*)pr)[tid];
  float v[8];
  const uint32_t w[4] = {raw.x, raw.y, raw.z, raw.w};
#pragma unroll
  for (int c = 0; c < 4; ++c) {
    v[2 * c]     = __uint_as_float(w[c] << 16);
    v[2 * c + 1] = __uint_as_float(w[c] & 0xffff0000u);
  }
  float mx = -3.38e38f;
#pragma unroll
  for (int i = 0; i < 8; ++i) mx = fmaxf(mx, v[i]);
#pragma unroll
  for (int o = 32; o >= 1; o >>= 1) mx = fmaxf(mx, __shfl_xor(mx, o));
  __shared__ float red[4];
  const int wave = tid >> 6, lane = tid & 63;
  if (lane == 0) red[wave] = mx;
  __syncthreads();
  mx = fmaxf(fmaxf(red[0], red[1]), fmaxf(red[2], red[3]));

  float s = 0.f;
#pragma unroll
  for (int i = 0; i < 8; ++i) { v[i] = __expf(v[i] - mx); s += v[i]; }
#pragma unroll
  for (int o = 32; o >= 1; o >>= 1) s += __shfl_xor(s, o);
  __syncthreads();
  if (lane == 0) red[wave] = s;
  __syncthreads();
  s = red[0] + red[1] + red[2] + red[3];
  const float inv = 1.f / s;

  uint4 o4;
  uint32_t* ow = (uint32_t*)&o4;
#pragma unroll
  for (int c = 0; c < 4; ++c) {
    const uint32_t lo = f2bf(v[2 * c] * inv);
    const uint32_t hi = f2bf(v[2 * c + 1] * inv);
    ow[c] = lo | (hi << 16);
  }
  ((uint4*)pr)[tid] = o4;
}

// ---------------------------------------------------------------------------
__global__ __launch_bounds__(256) void convert_kernel(
    const float* __restrict__ in, u16* __restrict__ out, int n)
{
  const int i = blockIdx.x * 256 + threadIdx.x;
  if (i < n) out[i] = f2bf(in[i]);
}

// Detect pad_mask storage: int32 0/1 has zero bytes at i%4!=0; u8 does not.
__global__ void detect_kernel(const unsigned char* __restrict__ m, int* __restrict__ flag)
{
  __shared__ int any;
  if (threadIdx.x == 0) any = 0;
  __syncthreads();
  int loc = 0;
  for (int i = threadIdx.x; i < B_ * S_; i += 256)
    if ((i & 3) && m[i]) loc = 1;
  if (loc) atomicOr(&any, 1);
  __syncthreads();
  if (threadIdx.x == 0) *flag = any;
}

// ---------------------------------------------------------------------------
extern "C" void kernel_launch(void* const* d_in, const int* in_sizes, int n_in,
                              void* d_out, int out_size, void* d_ws, size_t ws_size,
                              hipStream_t stream)
{
  const float* x    = (const float*)d_in[0];
  const void*  mask = d_in[1];
  const float* ln1w = (const float*)d_in[2];
  const float* ln1b = (const float*)d_in[3];
  const float* ln2w = (const float*)d_in[4];
  const float* ln2b = (const float*)d_in[5];
  const float* Wq   = (const float*)d_in[6];
  const float* bq   = (const float*)d_in[7];
  const float* Wk   = (const float*)d_in[8];
  const float* bk   = (const float*)d_in[9];
  const float* Wv   = (const float*)d_in[10];
  const float* bv   = (const float*)d_in[11];
  const float* W1   = (const float*)d_in[12];
  const float* b1   = (const float*)d_in[13];
  const float* W2   = (const float*)d_in[14];
  const float* b2   = (const float*)d_in[15];

  const size_t MB = 1024ull * 1024ull;
  char* p = (char*)d_ws;
  int* flag    = (int*)p;   p += 256;
  u16* Wqkvb   = (u16*)p;   p += (size_t)3 * E_ * E_ * 2;   // [Wq;Wk;Wv]
  u16* W1b     = (u16*)p;   p += (size_t)2 * E_ * E_ * 2;
  u16* W2b     = (u16*)p;   p += (size_t)2 * E_ * E_ * 2;
  float* bqkv  = (float*)p; p += 3 * E_ * 4;
  u16* normedb = (u16*)p;   p += (size_t)B_ * S_ * E_ * 2;
  char* chunk  = p;
  const size_t used  = (size_t)(p - (char*)d_ws);
  const size_t avail = (ws_size > used) ? (ws_size - used) : 0;

  // per-batch chunk unit: QK [S,2E] 8MB + Vt [E,S] 4MB + P [S,S] bf16 8MB
  int bc = 1;
  for (int c = 8; c >= 1; c >>= 1)
    if (avail >= 20 * MB * (size_t)c) { bc = c; break; }

  float* out = (float*)d_out;
  dim3 blk(256);

  detect_kernel<<<1, 256, 0, stream>>>((const unsigned char*)mask, flag);
  convert_kernel<<<(E_ * E_) / 256, blk, 0, stream>>>(Wq, Wqkvb, E_ * E_);
  convert_kernel<<<(E_ * E_) / 256, blk, 0, stream>>>(Wk, Wqkvb + (size_t)E_ * E_, E_ * E_);
  convert_kernel<<<(E_ * E_) / 256, blk, 0, stream>>>(Wv, Wqkvb + (size_t)2 * E_ * E_, E_ * E_);
  convert_kernel<<<(2 * E_ * E_) / 256, blk, 0, stream>>>(W1, W1b, 2 * E_ * E_);
  convert_kernel<<<(2 * E_ * E_) / 256, blk, 0, stream>>>(W2, W2b, 2 * E_ * E_);
  hipMemcpyAsync(bqkv, bq, E_ * sizeof(float), hipMemcpyDeviceToDevice, stream);
  hipMemcpyAsync(bqkv + E_, bk, E_ * sizeof(float), hipMemcpyDeviceToDevice, stream);
  hipMemcpyAsync(bqkv + 2 * E_, bv, E_ * sizeof(float), hipMemcpyDeviceToDevice, stream);

  layernorm_kernel<<<B_ * S_, blk, 0, stream>>>(x, ln1w, ln1b, normedb);

  for (int b0 = 0; b0 < B_; b0 += bc) {
    u16* QKc = (u16*)chunk;                           // [bc*S][2E]
    u16* Vt  = QKc + (size_t)bc * S_ * 2 * E_;        // [bc][E][S]
    u16* Pc  = Vt + (size_t)bc * E_ * S_;             // [bc][S][S] scores->P

    // [Q|K|Vt] = normed @ [Wq;Wk;Wv]^T + bqkv  (M = bc*S, N = 3E, split store)
    gemm_nt<true, false, false, true, false, false, true>
        <<<dim3(3 * E_ / 128, bc * S_ / 128, 1), blk, 0, stream>>>(
        normedb + (size_t)b0 * S_ * E_, Wqkvb, QKc, bqkv, nullptr,
        E_, E_, 2 * E_, E_, 0, 0, 0, nullptr, nullptr, 0, Vt);

    // scores = (Q @ K^T)/32, masked, bf16  (batched z=bc, M=N=S)
    gemm_nt<false, false, false, true, false, true, false>
        <<<dim3(S_ / 128, S_ / 128, bc), blk, 0, stream>>>(
        QKc, QKc + E_, Pc, nullptr, nullptr,
        2 * E_, 2 * E_, S_, E_,
        (long long)S_ * 2 * E_, (long long)S_ * 2 * E_, (long long)S_ * S_,
        mask, flag, b0, nullptr);

    // softmax in place
    softmax_bf16_kernel<<<bc * S_, blk, 0, stream>>>(Pc);

    // out = P @ Vt^T + x  (batched z=bc, M=S, N=E)
    gemm_nt<false, false, true, false, false, false, false>
        <<<dim3(E_ / 128, S_ / 128, bc), blk, 0, stream>>>(
        Pc, Vt, out + (size_t)b0 * S_ * E_, nullptr,
        x + (size_t)b0 * S_ * E_, S_, S_, E_, S_,
        (long long)S_ * S_, (long long)E_ * S_, (long long)S_ * E_,
        nullptr, nullptr, 0, nullptr);
  }

  layernorm_kernel<<<B_ * S_, blk, 0, stream>>>(out, ln2w, ln2b, normedb);

  // FFN row-chunked: h[mr][2E] bf16 lives in the chunk region
  size_t mr_sz = avail / ((size_t)2 * E_ * 2);
  int mr = (int)((mr_sz > 16384) ? 16384 : mr_sz);
  mr &= ~127;
  if (mr < 128) mr = 128;
  u16* hb = (u16*)chunk;
  for (int m0 = 0; m0 < B_ * S_; m0 += mr) {
    const int mm = (B_ * S_ - m0 < mr) ? (B_ * S_ - m0) : mr;
    // h = relu(normed2 @ W1^T + b1)
    gemm_nt<true, true, false, true, false, false, false>
        <<<dim3((2 * E_) / 128, mm / 128, 1), blk, 0, stream>>>(
        normedb + (size_t)m0 * E_, W1b, hb, b1, nullptr,
        E_, E_, 2 * E_, E_, 0, 0, 0, nullptr, nullptr, 0, nullptr);
    // out = h @ W2^T + b2 + out
    gemm_nt<true, false, true, false, false, false, false>
        <<<dim3(E_ / 128, mm / 128, 1), blk, 0, stream>>>(
        hb, W2b, out + (size_t)m0 * E_, b2, out + (size_t)m0 * E_,
        2 * E_, 2 * E_, E_, 2 * E_, 0, 0, 0, nullptr, nullptr, 0, nullptr);
  }
}

// Round 5
// 842.399 us; speedup vs baseline: 1.0289x; 1.0289x over previous
//
#include <hip/hip_runtime.h>
#include <hip/hip_bf16.h>
#include <cstdint>

#define B_ 8
#define S_ 2048
#define E_ 1024

using u16 = unsigned short;

typedef __bf16 bf16x8 __attribute__((ext_vector_type(8)));
typedef float f32x4 __attribute__((ext_vector_type(4)));

__device__ inline u16 f2bf(float f) {
  uint32_t u = __float_as_uint(f);
  uint32_t r = (u + 0x7fffu + ((u >> 16) & 1u)) >> 16;
  return (u16)r;
}

// ---------------------------------------------------------------------------
// Generic NT GEMM: C[m,n] = sum_k A[m,k] * B[n,k]  (bf16, K contiguous).
// 128x128 tile, BK=32, 4 waves x (64x64 via 4x4 MFMA 16x16x32). m97 staging.
// XCD-aware swizzle: linear id d -> XCD d%8 (assumed); each XCD walks 4x8
// block super-tiles (A 4 + B 8 panels ~3MB @K=1024 -> fits 4MB per-XCD L2).
// MASKSCALE: scores epilogue (x1/32, col mask -> -3e38, bf16 out).
// ---------------------------------------------------------------------------
template<bool HAS_BIAS, bool RELU, bool HAS_RES, bool OUT_BF16, bool MASKSCALE>
__global__ __launch_bounds__(256) void gemm_nt(
    const u16* __restrict__ A, const u16* __restrict__ B, void* __restrict__ C,
    const float* __restrict__ bias, const float* __restrict__ res,
    int lda, int ldb, int ldc, int K,
    long long strideA, long long strideB, long long strideC,
    const void* __restrict__ mask, const int* __restrict__ flag, int b0)
{
  __shared__ u16 lA[128 * 32];
  __shared__ u16 lB[128 * 32];

  const int tid  = threadIdx.x;
  const int lane = tid & 63;
  const int wave = tid >> 6;

  // ---- XCD-compacting block swizzle ----
  const int GM = 4, GN = 8;
  const int nbn = gridDim.x, nbm = gridDim.y, nz = gridDim.z;
  int bm, bn, bz;
  {
    const int total = nbn * nbm * nz;
    const long long lin = blockIdx.x +
        (long long)nbn * (blockIdx.y + (long long)nbm * blockIdx.z);
    if ((nbm % GM) == 0 && (nbn % GN) == 0 && (total % (8 * GM * GN)) == 0) {
      const int xcd = (int)(lin & 7);
      const int loc = (int)(lin >> 3);
      const int sper = GM * GN;                 // 32
      const int super = (loc / sper) * 8 + xcd;
      const int ins   = loc % sper;
      const int spz = (nbm / GM) * (nbn / GN);
      bz = super / spz;
      const int s2 = super % spz;
      const int sm = s2 % (nbm / GM);
      const int sn = s2 / (nbm / GM);
      bm = sm * GM + (ins % GM);
      bn = sn * GN + (ins / GM);
    } else { bm = blockIdx.y; bn = blockIdx.x; bz = blockIdx.z; }
  }

  const u16* Ab = A + (long long)bz * strideA;
  const u16* Bb = B + (long long)bz * strideB;

  const bool stageA = (wave < 2);
  const int  wpart  = (wave & 1) * 64;
  const int  srow   = lane >> 2;
  const int  scol   = (lane & 3) * 8;
  const int  ld     = stageA ? lda : ldb;
  const u16* gsrc   = stageA
      ? (Ab + (long long)(bm * 128 + wpart + srow) * lda + scol)
      : (Bb + (long long)(bn * 128 + wpart + srow) * ldb + scol);
  u16* ldst = (stageA ? lA : lB) + wpart * 32;

  f32x4 acc[4][4];
#pragma unroll
  for (int i = 0; i < 4; ++i)
#pragma unroll
    for (int j = 0; j < 4; ++j)
      acc[i][j] = (f32x4){0.f, 0.f, 0.f, 0.f};

  const int wm = (wave >> 1) * 64;
  const int wn = (wave & 1) * 64;
  const u16* pA = lA + (wm + (lane & 15)) * 32 + (lane >> 4) * 8;
  const u16* pB = lB + (wn + (lane & 15)) * 32 + (lane >> 4) * 8;

  const int nk = K >> 5;
  for (int kt = 0; kt < nk; ++kt) {
    __syncthreads();
    const u16* g = gsrc + kt * 32;
#pragma unroll
    for (int c = 0; c < 4; ++c) {
      __builtin_amdgcn_global_load_lds(
          (const __attribute__((address_space(1))) void*)(g + (long long)c * 16 * ld),
          (__attribute__((address_space(3))) void*)(ldst + c * 16 * 32),
          16, 0, 0);
    }
    __syncthreads();

    bf16x8 af[4], bfr[4];
#pragma unroll
    for (int i = 0; i < 4; ++i) af[i] = *(const bf16x8*)(pA + i * 16 * 32);
#pragma unroll
    for (int j = 0; j < 4; ++j) bfr[j] = *(const bf16x8*)(pB + j * 16 * 32);
#pragma unroll
    for (int i = 0; i < 4; ++i)
#pragma unroll
      for (int j = 0; j < 4; ++j)
        acc[i][j] = __builtin_amdgcn_mfma_f32_16x16x32_bf16(af[i], bfr[j], acc[i][j], 0, 0, 0);
  }

  // epilogue: C/D layout col = lane&15, row = (lane>>4)*4 + reg  [m89/m91]
  const int rb = wm + (lane >> 4) * 4;
  const int cb = wn + (lane & 15);
  const float* resb = (const float*)C;
  if (HAS_RES) resb = res + (long long)bz * strideC;
  u16*   cb16 = (u16*)C   + (long long)bz * strideC;
  float* cf32 = (float*)C + (long long)bz * strideC;

  bool u8m = false;
  const unsigned char* m8 = nullptr;
  const int* m32 = nullptr;
  if (MASKSCALE) {
    u8m = (*flag != 0);
    m8  = (const unsigned char*)mask + (long long)(b0 + bz) * S_;
    m32 = (const int*)mask + (long long)(b0 + bz) * S_;
  }

#pragma unroll
  for (int j = 0; j < 4; ++j) {
    const int gn = bn * 128 + cb + j * 16;
    const float bvv = HAS_BIAS ? bias[gn] : 0.f;
    bool masked = false;
    if (MASKSCALE) masked = u8m ? (m8[gn] != 0) : (m32[gn] != 0);
#pragma unroll
    for (int i = 0; i < 4; ++i) {
#pragma unroll
      for (int r = 0; r < 4; ++r) {
        const int gm = bm * 128 + rb + i * 16 + r;
        const long long idx = (long long)gm * ldc + gn;
        float v = acc[i][j][r] + bvv;
        if (MASKSCALE) { v *= 0.03125f; if (masked) v = -3.0e38f; }
        if (RELU) v = fmaxf(v, 0.f);
        if (HAS_RES) v += resb[idx];
        if (OUT_BF16) cb16[idx] = f2bf(v);
        else          cf32[idx] = v;
      }
    }
  }
}

// ---------------------------------------------------------------------------
__global__ __launch_bounds__(256) void layernorm_kernel(
    const float* __restrict__ x, const float* __restrict__ w,
    const float* __restrict__ b, u16* __restrict__ out)
{
  const int row = blockIdx.x;
  const int tid = threadIdx.x;
  const float4 v = ((const float4*)(x + (long long)row * E_))[tid];
  float s  = v.x + v.y + v.z + v.w;
  float s2 = v.x * v.x + v.y * v.y + v.z * v.z + v.w * v.w;
#pragma unroll
  for (int o = 32; o >= 1; o >>= 1) { s += __shfl_xor(s, o); s2 += __shfl_xor(s2, o); }
  __shared__ float rs[4], rs2[4];
  const int wave = tid >> 6, lane = tid & 63;
  if (lane == 0) { rs[wave] = s; rs2[wave] = s2; }
  __syncthreads();
  s  = rs[0] + rs[1] + rs[2] + rs[3];
  s2 = rs2[0] + rs2[1] + rs2[2] + rs2[3];
  const float mu   = s * (1.f / E_);
  const float var  = s2 * (1.f / E_) - mu * mu;
  const float rstd = rsqrtf(var + 1e-5f);
  const float4 wv = ((const float4*)w)[tid];
  const float4 bv = ((const float4*)b)[tid];
  ushort4 o;
  o.x = f2bf((v.x - mu) * rstd * wv.x + bv.x);
  o.y = f2bf((v.y - mu) * rstd * wv.y + bv.y);
  o.z = f2bf((v.z - mu) * rstd * wv.z + bv.z);
  o.w = f2bf((v.w - mu) * rstd * wv.w + bv.w);
  ((ushort4*)(out + (long long)row * E_))[tid] = o;
}

// ---------------------------------------------------------------------------
// in-place softmax over one bf16 row of S_ (scale+mask already applied)
__global__ __launch_bounds__(256) void softmax_bf16_kernel(u16* __restrict__ sp)
{
  const int row = blockIdx.x;
  const int tid = threadIdx.x;
  u16* pr = sp + (long long)row * S_;
  uint4 raw = ((uint4*)pr)[tid];
  float v[8];
  const uint32_t w[4] = {raw.x, raw.y, raw.z, raw.w};
#pragma unroll
  for (int c = 0; c < 4; ++c) {
    v[2 * c]     = __uint_as_float(w[c] << 16);
    v[2 * c + 1] = __uint_as_float(w[c] & 0xffff0000u);
  }
  float mx = -3.38e38f;
#pragma unroll
  for (int i = 0; i < 8; ++i) mx = fmaxf(mx, v[i]);
#pragma unroll
  for (int o = 32; o >= 1; o >>= 1) mx = fmaxf(mx, __shfl_xor(mx, o));
  __shared__ float red[4];
  const int wave = tid >> 6, lane = tid & 63;
  if (lane == 0) red[wave] = mx;
  __syncthreads();
  mx = fmaxf(fmaxf(red[0], red[1]), fmaxf(red[2], red[3]));

  float s = 0.f;
#pragma unroll
  for (int i = 0; i < 8; ++i) { v[i] = __expf(v[i] - mx); s += v[i]; }
#pragma unroll
  for (int o = 32; o >= 1; o >>= 1) s += __shfl_xor(s, o);
  __syncthreads();
  if (lane == 0) red[wave] = s;
  __syncthreads();
  s = red[0] + red[1] + red[2] + red[3];
  const float inv = 1.f / s;

  uint4 o4;
  uint32_t* ow = (uint32_t*)&o4;
#pragma unroll
  for (int c = 0; c < 4; ++c) {
    const uint32_t lo = f2bf(v[2 * c] * inv);
    const uint32_t hi = f2bf(v[2 * c + 1] * inv);
    ow[c] = lo | (hi << 16);
  }
  ((uint4*)pr)[tid] = o4;
}

// ---------------------------------------------------------------------------
// V slice of QKV [bc*S, 3E] (cols [2E,3E)) -> Vt [bc][E][S], 32x32 LDS tiles
__global__ __launch_bounds__(256) void transpose_kernel(
    const u16* __restrict__ QKV, u16* __restrict__ Vt)
{
  __shared__ u16 tile[32][33];
  const int bl = blockIdx.z;
  const int e0 = blockIdx.x * 32, s0 = blockIdx.y * 32;
  const int tx = threadIdx.x & 31, ty = threadIdx.x >> 5;   // ty 0..7
  const u16* src = QKV + ((long long)bl * S_ + s0) * (3 * E_) + 2 * E_ + e0;
#pragma unroll
  for (int r = 0; r < 32; r += 8)
    tile[ty + r][tx] = src[(long long)(ty + r) * (3 * E_) + tx];
  __syncthreads();
  u16* dst = Vt + ((long long)bl * E_ + e0) * S_ + s0;
#pragma unroll
  for (int r = 0; r < 32; r += 8)
    dst[(long long)(ty + r) * S_ + tx] = tile[tx][ty + r];
}

// ---------------------------------------------------------------------------
__global__ __launch_bounds__(256) void convert_kernel(
    const float* __restrict__ in, u16* __restrict__ out, int n)
{
  const int i = blockIdx.x * 256 + threadIdx.x;
  if (i < n) out[i] = f2bf(in[i]);
}

// Detect pad_mask storage: int32 0/1 has zero bytes at i%4!=0; u8 does not.
__global__ void detect_kernel(const unsigned char* __restrict__ m, int* __restrict__ flag)
{
  __shared__ int any;
  if (threadIdx.x == 0) any = 0;
  __syncthreads();
  int loc = 0;
  for (int i = threadIdx.x; i < B_ * S_; i += 256)
    if ((i & 3) && m[i]) loc = 1;
  if (loc) atomicOr(&any, 1);
  __syncthreads();
  if (threadIdx.x == 0) *flag = any;
}

// ---------------------------------------------------------------------------
extern "C" void kernel_launch(void* const* d_in, const int* in_sizes, int n_in,
                              void* d_out, int out_size, void* d_ws, size_t ws_size,
                              hipStream_t stream)
{
  const float* x    = (const float*)d_in[0];
  const void*  mask = d_in[1];
  const float* ln1w = (const float*)d_in[2];
  const float* ln1b = (const float*)d_in[3];
  const float* ln2w = (const float*)d_in[4];
  const float* ln2b = (const float*)d_in[5];
  const float* Wq   = (const float*)d_in[6];
  const float* bq   = (const float*)d_in[7];
  const float* Wk   = (const float*)d_in[8];
  const float* bk   = (const float*)d_in[9];
  const float* Wv   = (const float*)d_in[10];
  const float* bv   = (const float*)d_in[11];
  const float* W1   = (const float*)d_in[12];
  const float* b1   = (const float*)d_in[13];
  const float* W2   = (const float*)d_in[14];
  const float* b2   = (const float*)d_in[15];

  const size_t MB = 1024ull * 1024ull;
  char* p = (char*)d_ws;
  int* flag    = (int*)p;   p += 256;
  u16* Wqkvb   = (u16*)p;   p += (size_t)3 * E_ * E_ * 2;   // [Wq;Wk;Wv]
  u16* W1b     = (u16*)p;   p += (size_t)2 * E_ * E_ * 2;
  u16* W2b     = (u16*)p;   p += (size_t)2 * E_ * E_ * 2;
  float* bqkv  = (float*)p; p += 3 * E_ * 4;
  u16* normedb = (u16*)p;   p += (size_t)B_ * S_ * E_ * 2;
  char* chunk  = p;
  const size_t used  = (size_t)(p - (char*)d_ws);
  const size_t avail = (ws_size > used) ? (ws_size - used) : 0;

  // per-batch unit: QKV [S,3E] 12MB + Vt [E,S] 4MB + P [S,S] bf16 8MB = 24MB
  int bc = 1;
  for (int c = 8; c >= 1; c >>= 1)
    if (avail >= 24 * MB * (size_t)c) { bc = c; break; }

  float* out = (float*)d_out;
  dim3 blk(256);

  detect_kernel<<<1, 256, 0, stream>>>((const unsigned char*)mask, flag);
  convert_kernel<<<(E_ * E_) / 256, blk, 0, stream>>>(Wq, Wqkvb, E_ * E_);
  convert_kernel<<<(E_ * E_) / 256, blk, 0, stream>>>(Wk, Wqkvb + (size_t)E_ * E_, E_ * E_);
  convert_kernel<<<(E_ * E_) / 256, blk, 0, stream>>>(Wv, Wqkvb + (size_t)2 * E_ * E_, E_ * E_);
  convert_kernel<<<(2 * E_ * E_) / 256, blk, 0, stream>>>(W1, W1b, 2 * E_ * E_);
  convert_kernel<<<(2 * E_ * E_) / 256, blk, 0, stream>>>(W2, W2b, 2 * E_ * E_);
  hipMemcpyAsync(bqkv, bq, E_ * sizeof(float), hipMemcpyDeviceToDevice, stream);
  hipMemcpyAsync(bqkv + E_, bk, E_ * sizeof(float), hipMemcpyDeviceToDevice, stream);
  hipMemcpyAsync(bqkv + 2 * E_, bv, E_ * sizeof(float), hipMemcpyDeviceToDevice, stream);

  layernorm_kernel<<<B_ * S_, blk, 0, stream>>>(x, ln1w, ln1b, normedb);

  for (int b0 = 0; b0 < B_; b0 += bc) {
    u16* QKVc = (u16*)chunk;                          // [bc*S][3E] row-major
    u16* Vt   = QKVc + (size_t)bc * S_ * 3 * E_;      // [bc][E][S]
    u16* Pc   = Vt + (size_t)bc * E_ * S_;            // [bc][S][S] scores->P

    // [Q|K|V] = normed @ [Wq;Wk;Wv]^T + bqkv  (M = bc*S, N = 3E, coalesced)
    gemm_nt<true, false, false, true, false>
        <<<dim3(3 * E_ / 128, bc * S_ / 128, 1), blk, 0, stream>>>(
        normedb + (size_t)b0 * S_ * E_, Wqkvb, QKVc, bqkv, nullptr,
        E_, E_, 3 * E_, E_, 0, 0, 0, nullptr, nullptr, 0);

    // Vt = transpose of V slice
    transpose_kernel<<<dim3(E_ / 32, S_ / 32, bc), blk, 0, stream>>>(QKVc, Vt);

    // scores = (Q @ K^T)/32, masked, bf16  (batched z=bc, M=N=S)
    gemm_nt<false, false, false, true, true>
        <<<dim3(S_ / 128, S_ / 128, bc), blk, 0, stream>>>(
        QKVc, QKVc + E_, Pc, nullptr, nullptr,
        3 * E_, 3 * E_, S_, E_,
        (long long)S_ * 3 * E_, (long long)S_ * 3 * E_, (long long)S_ * S_,
        mask, flag, b0);

    // softmax in place
    softmax_bf16_kernel<<<bc * S_, blk, 0, stream>>>(Pc);

    // out = P @ Vt^T + x  (batched z=bc, M=S, N=E)
    gemm_nt<false, false, true, false, false>
        <<<dim3(E_ / 128, S_ / 128, bc), blk, 0, stream>>>(
        Pc, Vt, out + (size_t)b0 * S_ * E_, nullptr,
        x + (size_t)b0 * S_ * E_, S_, S_, E_, S_,
        (long long)S_ * S_, (long long)E_ * S_, (long long)S_ * E_,
        nullptr, nullptr, 0);
  }

  layernorm_kernel<<<B_ * S_, blk, 0, stream>>>(out, ln2w, ln2b, normedb);

  // FFN row-chunked: h[mr][2E] bf16 lives in the chunk region
  size_t mr_sz = avail / ((size_t)2 * E_ * 2);
  int mr = (int)((mr_sz > 16384) ? 16384 : mr_sz);
  mr &= ~127;
  if (mr < 128) mr = 128;
  u16* hb = (u16*)chunk;
  for (int m0 = 0; m0 < B_ * S_; m0 += mr) {
    const int mm = (B_ * S_ - m0 < mr) ? (B_ * S_ - m0) : mr;
    // h = relu(normed2 @ W1^T + b1)
    gemm_nt<true, true, false, true, false>
        <<<dim3((2 * E_) / 128, mm / 128, 1), blk, 0, stream>>>(
        normedb + (size_t)m0 * E_, W1b, hb, b1, nullptr,
        E_, E_, 2 * E_, E_, 0, 0, 0, nullptr, nullptr, 0);
    // out = h @ W2^T + b2 + out
    gemm_nt<true, false, true, false, false>
        <<<dim3(E_ / 128, mm / 128, 1), blk, 0, stream>>>(
        hb, W2b, out + (size_t)m0 * E_, b2, out + (size_t)m0 * E_,
        2 * E_, 2 * E_, E_, 2 * E_, 0, 0, 0, nullptr, nullptr, 0);
  }
}

// Round 6
// 780.753 us; speedup vs baseline: 1.1101x; 1.0790x over previous
//
#include <hip/hip_runtime.h>
#include <hip/hip_bf16.h>
#include <cstdint>

#define B_ 8
#define S_ 2048
#define E_ 1024

using u16 = unsigned short;

typedef __bf16 bf16x8 __attribute__((ext_vector_type(8)));
typedef float f32x4 __attribute__((ext_vector_type(4)));

__device__ inline u16 f2bf(float f) {
  uint32_t u = __float_as_uint(f);
  uint32_t r = (u + 0x7fffu + ((u >> 16) & 1u)) >> 16;
  return (u16)r;
}

// ---------------------------------------------------------------------------
// Generic NT GEMM: C[m,n] = sum_k A[m,k]*B[n,k] (bf16, K contiguous).
// 128x128 tile, BK=32, 4 waves x 64x64 (4x4 MFMA 16x16x32), m97 staging,
// XCD-compacting swizzle (id d -> XCD d%8, 4x8 super-tiles).
// SCORES : scores epilogue: x1/32, col>=count -> -3e38, bf16; early-out on
//          bn*128 >= cnt_pad[bz].
// GATHER_A: A rows gathered through cidx[bz*S_ + m] (per-lane global addrs,
//          LDS side stays lane-contiguous); early-out on bm*128 >= cnt_pad.
// RUNTK  : K dimension = cnt_pad[bz] (device-read, block-uniform).
// ---------------------------------------------------------------------------
template<bool HAS_BIAS, bool RELU, bool HAS_RES, bool OUT_BF16, bool SCORES,
         bool GATHER_A, bool RUNTK>
__global__ __launch_bounds__(256) void gemm_nt(
    const u16* __restrict__ A, const u16* __restrict__ B, void* __restrict__ C,
    const float* __restrict__ bias, const float* __restrict__ res,
    int lda, int ldb, int ldc, int K,
    long long strideA, long long strideB, long long strideC,
    const int* __restrict__ cidx, const int* __restrict__ cnt)
{
  __shared__ u16 lA[128 * 32];
  __shared__ u16 lB[128 * 32];

  const int tid  = threadIdx.x;
  const int lane = tid & 63;
  const int wave = tid >> 6;

  // ---- XCD-compacting block swizzle ----
  const int GM = 4, GN = 8;
  const int nbn = gridDim.x, nbm = gridDim.y, nz = gridDim.z;
  int bm, bn, bz;
  {
    const int total = nbn * nbm * nz;
    const long long lin = blockIdx.x +
        (long long)nbn * (blockIdx.y + (long long)nbm * blockIdx.z);
    if ((nbm % GM) == 0 && (nbn % GN) == 0 && (total % (8 * GM * GN)) == 0) {
      const int xcd = (int)(lin & 7);
      const int loc = (int)(lin >> 3);
      const int sper = GM * GN;
      const int super = (loc / sper) * 8 + xcd;
      const int ins   = loc % sper;
      const int spz = (nbm / GM) * (nbn / GN);
      bz = super / spz;
      const int s2 = super % spz;
      const int sm = s2 % (nbm / GM);
      const int sn = s2 / (nbm / GM);
      bm = sm * GM + (ins % GM);
      bn = sn * GN + (ins / GM);
    } else { bm = blockIdx.y; bn = blockIdx.x; bz = blockIdx.z; }
  }

  int count = 0, cpad = 0;
  if (SCORES || GATHER_A || RUNTK) {
    count = cnt[bz * 2];
    cpad  = cnt[bz * 2 + 1];
    if (GATHER_A && bm * 128 >= cpad) return;   // block-uniform, pre-barrier
    if (SCORES   && bn * 128 >= cpad) return;
  }
  const int Keff = RUNTK ? cpad : K;

  const u16* Ab = A + (long long)bz * strideA;
  const u16* Bb = B + (long long)bz * strideB;

  const bool stageA = (wave < 2);
  const int  wpart  = (wave & 1) * 64;
  const int  srow   = lane >> 2;        // 0..15
  const int  scol   = (lane & 3) * 8;   // bf16 col offset
  const int  ld     = stageA ? lda : ldb;

  // per-chunk source offsets (c = 0..3 covers rows wpart+16c+srow)
  long long goff[4];
  if (GATHER_A && stageA) {
    const int* cx = cidx;
#pragma unroll
    for (int c = 0; c < 4; ++c) {
      const int r = cx[(long long)bz * S_ + bm * 128 + wpart + 16 * c + srow];
      goff[c] = (long long)r * lda + scol;
    }
  } else {
    const int rbase = (stageA ? bm : bn) * 128 + wpart + srow;
#pragma unroll
    for (int c = 0; c < 4; ++c)
      goff[c] = (long long)(rbase + 16 * c) * ld + scol;
  }
  const u16* gb = stageA ? Ab : Bb;
  u16* ldst = (stageA ? lA : lB) + wpart * 32;

  f32x4 acc[4][4];
#pragma unroll
  for (int i = 0; i < 4; ++i)
#pragma unroll
    for (int j = 0; j < 4; ++j)
      acc[i][j] = (f32x4){0.f, 0.f, 0.f, 0.f};

  const int wm = (wave >> 1) * 64;
  const int wn = (wave & 1) * 64;
  const u16* pA = lA + (wm + (lane & 15)) * 32 + (lane >> 4) * 8;
  const u16* pB = lB + (wn + (lane & 15)) * 32 + (lane >> 4) * 8;

  const int nk = Keff >> 5;
  for (int kt = 0; kt < nk; ++kt) {
    __syncthreads();
#pragma unroll
    for (int c = 0; c < 4; ++c) {
      __builtin_amdgcn_global_load_lds(
          (const __attribute__((address_space(1))) void*)(gb + goff[c] + kt * 32),
          (__attribute__((address_space(3))) void*)(ldst + c * 16 * 32),
          16, 0, 0);
    }
    __syncthreads();

    bf16x8 af[4], bfr[4];
#pragma unroll
    for (int i = 0; i < 4; ++i) af[i] = *(const bf16x8*)(pA + i * 16 * 32);
#pragma unroll
    for (int j = 0; j < 4; ++j) bfr[j] = *(const bf16x8*)(pB + j * 16 * 32);
#pragma unroll
    for (int i = 0; i < 4; ++i)
#pragma unroll
      for (int j = 0; j < 4; ++j)
        acc[i][j] = __builtin_amdgcn_mfma_f32_16x16x32_bf16(af[i], bfr[j], acc[i][j], 0, 0, 0);
  }

  // epilogue: C/D layout col = lane&15, row = (lane>>4)*4 + reg  [m89/m91]
  const int rb = wm + (lane >> 4) * 4;
  const int cb = wn + (lane & 15);
  const float* resb = (const float*)C;
  if (HAS_RES) resb = res + (long long)bz * strideC;
  u16*   cb16 = (u16*)C   + (long long)bz * strideC;
  float* cf32 = (float*)C + (long long)bz * strideC;

#pragma unroll
  for (int j = 0; j < 4; ++j) {
    const int gn = bn * 128 + cb + j * 16;
    const float bvv = HAS_BIAS ? bias[gn] : 0.f;
    const bool cmask = SCORES && (gn >= count);
#pragma unroll
    for (int i = 0; i < 4; ++i) {
#pragma unroll
      for (int r = 0; r < 4; ++r) {
        const int gm = bm * 128 + rb + i * 16 + r;
        const long long idx = (long long)gm * ldc + gn;
        float v = acc[i][j][r] + bvv;
        if (SCORES) { v *= 0.03125f; if (cmask) v = -3.0e38f; }
        if (RELU) v = fmaxf(v, 0.f);
        if (HAS_RES) v += resb[idx];
        if (OUT_BF16) cb16[idx] = f2bf(v);
        else          cf32[idx] = v;
      }
    }
  }
}

// ---------------------------------------------------------------------------
__global__ __launch_bounds__(256) void layernorm_kernel(
    const float* __restrict__ x, const float* __restrict__ w,
    const float* __restrict__ b, u16* __restrict__ out)
{
  const int row = blockIdx.x;
  const int tid = threadIdx.x;
  const float4 v = ((const float4*)(x + (long long)row * E_))[tid];
  float s  = v.x + v.y + v.z + v.w;
  float s2 = v.x * v.x + v.y * v.y + v.z * v.z + v.w * v.w;
#pragma unroll
  for (int o = 32; o >= 1; o >>= 1) { s += __shfl_xor(s, o); s2 += __shfl_xor(s2, o); }
  __shared__ float rs[4], rs2[4];
  const int wave = tid >> 6, lane = tid & 63;
  if (lane == 0) { rs[wave] = s; rs2[wave] = s2; }
  __syncthreads();
  s  = rs[0] + rs[1] + rs[2] + rs[3];
  s2 = rs2[0] + rs2[1] + rs2[2] + rs2[3];
  const float mu   = s * (1.f / E_);
  const float var  = s2 * (1.f / E_) - mu * mu;
  const float rstd = rsqrtf(var + 1e-5f);
  const float4 wv = ((const float4*)w)[tid];
  const float4 bv = ((const float4*)b)[tid];
  ushort4 o;
  o.x = f2bf((v.x - mu) * rstd * wv.x + bv.x);
  o.y = f2bf((v.y - mu) * rstd * wv.y + bv.y);
  o.z = f2bf((v.z - mu) * rstd * wv.z + bv.z);
  o.w = f2bf((v.w - mu) * rstd * wv.w + bv.w);
  ((ushort4*)(out + (long long)row * E_))[tid] = o;
}

// ---------------------------------------------------------------------------
// in-place softmax over one bf16 row; only cols < cnt_pad touched
__global__ __launch_bounds__(256) void softmax_bf16_kernel(
    u16* __restrict__ sp, const int* __restrict__ cnt)
{
  const int row = blockIdx.x;
  const int bz  = row >> 11;            // row / S_
  const int tid = threadIdx.x;
  const int cpad = cnt[bz * 2 + 1];
  const bool act = (tid * 8) < cpad;
  u16* pr = sp + (long long)row * S_;

  float v[8];
  if (act) {
    const uint4 raw = ((const uint4*)pr)[tid];
    const uint32_t w[4] = {raw.x, raw.y, raw.z, raw.w};
#pragma unroll
    for (int c = 0; c < 4; ++c) {
      v[2 * c]     = __uint_as_float(w[c] << 16);
      v[2 * c + 1] = __uint_as_float(w[c] & 0xffff0000u);
    }
  } else {
#pragma unroll
    for (int i = 0; i < 8; ++i) v[i] = -3.38e38f;
  }
  float mx = -3.38e38f;
#pragma unroll
  for (int i = 0; i < 8; ++i) mx = fmaxf(mx, v[i]);
#pragma unroll
  for (int o = 32; o >= 1; o >>= 1) mx = fmaxf(mx, __shfl_xor(mx, o));
  __shared__ float red[4];
  const int wave = tid >> 6, lane = tid & 63;
  if (lane == 0) red[wave] = mx;
  __syncthreads();
  mx = fmaxf(fmaxf(red[0], red[1]), fmaxf(red[2], red[3]));

  float s = 0.f;
#pragma unroll
  for (int i = 0; i < 8; ++i) { v[i] = __expf(v[i] - mx); s += v[i]; }
#pragma unroll
  for (int o = 32; o >= 1; o >>= 1) s += __shfl_xor(s, o);
  __syncthreads();
  if (lane == 0) red[wave] = s;
  __syncthreads();
  s = red[0] + red[1] + red[2] + red[3];
  const float inv = 1.f / s;

  if (act) {
    uint4 o4;
    uint32_t* ow = (uint32_t*)&o4;
#pragma unroll
    for (int c = 0; c < 4; ++c) {
      const uint32_t lo = f2bf(v[2 * c] * inv);
      const uint32_t hi = f2bf(v[2 * c + 1] * inv);
      ow[c] = lo | (hi << 16);
    }
    ((uint4*)pr)[tid] = o4;
  }
}

// ---------------------------------------------------------------------------
// V slice of KVc [bc][S_,2E] (cols [E,2E)) -> Vt [bc][E][S_], early-out > cpad
__global__ __launch_bounds__(256) void transpose_kernel(
    const u16* __restrict__ KVc, u16* __restrict__ Vt, const int* __restrict__ cnt)
{
  const int bl = blockIdx.z;
  const int s0 = blockIdx.y * 32;
  if (s0 >= cnt[bl * 2 + 1]) return;
  __shared__ u16 tile[32][33];
  const int e0 = blockIdx.x * 32;
  const int tx = threadIdx.x & 31, ty = threadIdx.x >> 5;   // ty 0..7
  const u16* src = KVc + ((long long)bl * S_ + s0) * (2 * E_) + E_ + e0;
#pragma unroll
  for (int r = 0; r < 32; r += 8)
    tile[ty + r][tx] = src[(long long)(ty + r) * (2 * E_) + tx];
  __syncthreads();
  u16* dst = Vt + ((long long)bl * E_ + e0) * S_ + s0;
#pragma unroll
  for (int r = 0; r < 32; r += 8)
    dst[(long long)(ty + r) * S_ + tx] = tile[tx][ty + r];
}

// ---------------------------------------------------------------------------
// fused weight converts + bias concat
__global__ __launch_bounds__(256) void prep_kernel(
    const float* __restrict__ Wq, const float* __restrict__ Wk,
    const float* __restrict__ Wv, const float* __restrict__ W1,
    const float* __restrict__ W2, const float* __restrict__ bk,
    const float* __restrict__ bv,
    u16* __restrict__ Wqb, u16* __restrict__ Wkvb,
    u16* __restrict__ W1b, u16* __restrict__ W2b, float* __restrict__ bkv)
{
  const int N1 = E_ * E_;
  const long long i = (long long)blockIdx.x * 256 + threadIdx.x;
  if (i < N1)               Wqb[i] = f2bf(Wq[i]);
  else if (i < 2LL * N1)    Wkvb[i - N1] = f2bf(Wk[i - N1]);
  else if (i < 3LL * N1)    Wkvb[N1 + (i - 2LL * N1)] = f2bf(Wv[i - 2LL * N1]);
  else if (i < 5LL * N1)    W1b[i - 3LL * N1] = f2bf(W1[i - 3LL * N1]);
  else if (i < 7LL * N1)    W2b[i - 5LL * N1] = f2bf(W2[i - 5LL * N1]);
  else if (i < 7LL * N1 + 2 * E_) {
    const int j = (int)(i - 7LL * N1);
    bkv[j] = (j < E_) ? bk[j] : bv[j - E_];
  }
}

// Detect pad_mask storage: int32 0/1 has zero bytes at i%4!=0; u8 does not.
__global__ void detect_kernel(const unsigned char* __restrict__ m, int* __restrict__ flag)
{
  __shared__ int any;
  if (threadIdx.x == 0) any = 0;
  __syncthreads();
  int loc = 0;
  for (int i = threadIdx.x; i < B_ * S_; i += 256)
    if ((i & 3) && m[i]) loc = 1;
  if (loc) atomicOr(&any, 1);
  __syncthreads();
  if (threadIdx.x == 0) *flag = any;
}

// per-batch compaction: cidx[b][j] = j-th unmasked key, cnt[b] = {count, pad128}
__global__ __launch_bounds__(256) void compact_kernel(
    const void* __restrict__ mask, const int* __restrict__ flag,
    int* __restrict__ cidx, int* __restrict__ cnt)
{
  const int b = blockIdx.x;
  const int tid = threadIdx.x, lane = tid & 63, wave = tid >> 6;
  const bool u8m = (*flag != 0);
  const unsigned char* m8 = (const unsigned char*)mask + (long long)b * S_;
  const int* m32 = (const int*)mask + (long long)b * S_;

  int keep[8]; int my = 0;
#pragma unroll
  for (int j = 0; j < 8; ++j) {
    const int s = tid * 8 + j;
    const bool k = u8m ? (m8[s] == 0) : (m32[s] == 0);
    keep[j] = k ? 1 : 0; my += keep[j];
  }
  int pre = my;
#pragma unroll
  for (int o = 1; o < 64; o <<= 1) {
    const int n = __shfl_up(pre, o);
    if (lane >= o) pre += n;
  }
  __shared__ int wsum[4];
  if (lane == 63) wsum[wave] = pre;
  __syncthreads();
  int wbase = 0;
#pragma unroll
  for (int w = 0; w < 4; ++w) if (w < wave) wbase += wsum[w];
  int pos = wbase + pre - my;
  int* cx = cidx + (long long)b * S_;
#pragma unroll
  for (int j = 0; j < 8; ++j)
    if (keep[j]) cx[pos++] = tid * 8 + j;
  const int total = wsum[0] + wsum[1] + wsum[2] + wsum[3];
  const int cpad = (total + 127) & ~127;
  for (int i = total + tid; i < cpad; i += 256) cx[i] = 0;
  if (tid == 0) { cnt[b * 2] = total; cnt[b * 2 + 1] = cpad; }
}

// ---------------------------------------------------------------------------
extern "C" void kernel_launch(void* const* d_in, const int* in_sizes, int n_in,
                              void* d_out, int out_size, void* d_ws, size_t ws_size,
                              hipStream_t stream)
{
  const float* x    = (const float*)d_in[0];
  const void*  mask = d_in[1];
  const float* ln1w = (const float*)d_in[2];
  const float* ln1b = (const float*)d_in[3];
  const float* ln2w = (const float*)d_in[4];
  const float* ln2b = (const float*)d_in[5];
  const float* Wq   = (const float*)d_in[6];
  const float* bq   = (const float*)d_in[7];
  const float* Wk   = (const float*)d_in[8];
  const float* bk   = (const float*)d_in[9];
  const float* Wv   = (const float*)d_in[10];
  const float* bv   = (const float*)d_in[11];
  const float* W1   = (const float*)d_in[12];
  const float* b1   = (const float*)d_in[13];
  const float* W2   = (const float*)d_in[14];
  const float* b2   = (const float*)d_in[15];

  const size_t MB = 1024ull * 1024ull;
  char* p = (char*)d_ws;
  int* flag    = (int*)p;   p += 256;
  int* cnt     = (int*)p;   p += 256;
  int* cidx    = (int*)p;   p += (size_t)B_ * S_ * 4;
  u16* Wqb     = (u16*)p;   p += (size_t)E_ * E_ * 2;
  u16* Wkvb    = (u16*)p;   p += (size_t)2 * E_ * E_ * 2;   // [Wk;Wv]
  u16* W1b     = (u16*)p;   p += (size_t)2 * E_ * E_ * 2;
  u16* W2b     = (u16*)p;   p += (size_t)2 * E_ * E_ * 2;
  float* bkv   = (float*)p; p += 2 * E_ * 4;
  u16* normedb = (u16*)p;   p += (size_t)B_ * S_ * E_ * 2;
  char* chunk  = p;
  const size_t used  = (size_t)(p - (char*)d_ws);
  const size_t avail = (ws_size > used) ? (ws_size - used) : 0;

  // per-batch unit: Q [S,E] 4MB + KVc [S,2E] 8MB + Vt [E,S] 4MB + P 8MB = 24MB
  int bc = 1;
  for (int c = 8; c >= 1; c >>= 1)
    if (avail >= 24 * MB * (size_t)c) { bc = c; break; }

  float* out = (float*)d_out;
  dim3 blk(256);

  detect_kernel<<<1, 256, 0, stream>>>((const unsigned char*)mask, flag);
  compact_kernel<<<B_, blk, 0, stream>>>(mask, flag, cidx, cnt);
  {
    const long long tot = 7LL * E_ * E_ + 2 * E_;
    prep_kernel<<<(int)((tot + 255) / 256), blk, 0, stream>>>(
        Wq, Wk, Wv, W1, W2, bk, bv, Wqb, Wkvb, W1b, W2b, bkv);
  }

  layernorm_kernel<<<B_ * S_, blk, 0, stream>>>(x, ln1w, ln1b, normedb);

  for (int b0 = 0; b0 < B_; b0 += bc) {
    u16* Qc  = (u16*)chunk;                          // [bc*S][E]
    u16* KVc = Qc + (size_t)bc * S_ * E_;            // [bc][S][2E] (compact rows)
    u16* Vt  = KVc + (size_t)bc * S_ * 2 * E_;       // [bc][E][S]
    u16* Pc  = Vt + (size_t)bc * E_ * S_;            // [bc][S][S] scores->P
    const int* cntb  = cnt + b0 * 2;
    const int* cidxb = cidx + (size_t)b0 * S_;

    // Q = normed @ Wq^T + bq  (all rows, flat M = bc*S)
    gemm_nt<true, false, false, true, false, false, false>
        <<<dim3(E_ / 128, bc * S_ / 128, 1), blk, 0, stream>>>(
        normedb + (size_t)b0 * S_ * E_, Wqb, Qc, bq, nullptr,
        E_, E_, E_, E_, 0, 0, 0, nullptr, nullptr);

    // KV_compact = normed[cidx] @ [Wk;Wv]^T + bkv  (z=bc, M early-out)
    gemm_nt<true, false, false, true, false, true, false>
        <<<dim3(2 * E_ / 128, S_ / 128, bc), blk, 0, stream>>>(
        normedb + (size_t)b0 * S_ * E_, Wkvb, KVc, bkv, nullptr,
        E_, E_, 2 * E_, E_,
        (long long)S_ * E_, 0, (long long)S_ * 2 * E_, cidxb, cntb);

    // Vt = transpose of V slice (compact cols only)
    transpose_kernel<<<dim3(E_ / 32, S_ / 32, bc), blk, 0, stream>>>(KVc, Vt, cntb);

    // scores = (Q @ Kc^T)/32, col>=count -> -inf, bf16 (N early-out)
    gemm_nt<false, false, false, true, true, false, false>
        <<<dim3(S_ / 128, S_ / 128, bc), blk, 0, stream>>>(
        Qc, KVc, Pc, nullptr, nullptr,
        E_, 2 * E_, S_, E_,
        (long long)S_ * E_, (long long)S_ * 2 * E_, (long long)S_ * S_,
        nullptr, cntb);

    // softmax in place over compact width
    softmax_bf16_kernel<<<bc * S_, blk, 0, stream>>>(Pc, cntb);

    // out = P @ Vt^T + x  (K = cnt_pad runtime)
    gemm_nt<false, false, true, false, false, false, true>
        <<<dim3(E_ / 128, S_ / 128, bc), blk, 0, stream>>>(
        Pc, Vt, out + (size_t)b0 * S_ * E_, nullptr,
        x + (size_t)b0 * S_ * E_, S_, S_, E_, S_,
        (long long)S_ * S_, (long long)E_ * S_, (long long)S_ * E_,
        nullptr, cntb);
  }

  layernorm_kernel<<<B_ * S_, blk, 0, stream>>>(out, ln2w, ln2b, normedb);

  // FFN row-chunked: h[mr][2E] bf16 lives in the chunk region
  size_t mr_sz = avail / ((size_t)2 * E_ * 2);
  int mr = (int)((mr_sz > 16384) ? 16384 : mr_sz);
  mr &= ~127;
  if (mr < 128) mr = 128;
  u16* hb = (u16*)chunk;
  for (int m0 = 0; m0 < B_ * S_; m0 += mr) {
    const int mm = (B_ * S_ - m0 < mr) ? (B_ * S_ - m0) : mr;
    // h = relu(normed2 @ W1^T + b1)
    gemm_nt<true, true, false, true, false, false, false>
        <<<dim3((2 * E_) / 128, mm / 128, 1), blk, 0, stream>>>(
        normedb + (size_t)m0 * E_, W1b, hb, b1, nullptr,
        E_, E_, 2 * E_, E_, 0, 0, 0, nullptr, nullptr);
    // out = h @ W2^T + b2 + out
    gemm_nt<true, false, true, false, false, false, false>
        <<<dim3(E_ / 128, mm / 128, 1), blk, 0, stream>>>(
        hb, W2b, out + (size_t)m0 * E_, b2, out + (size_t)m0 * E_,
        2 * E_, 2 * E_, E_, 2 * E_, 0, 0, 0, nullptr, nullptr);
  }
}